// Round 7
// baseline (237.994 us; speedup 1.0000x reference)
//
#include <hip/hip_runtime.h>
#include <hip/hip_bf16.h>
#include <math.h>

// Chamfer distance via K-packed MFMA, B=8, N=M=8192, D=3, fp32.
//   C[m][n] = q_m.r_n - 0.5*||r_n||^2 via ONE v_mfma_f32_32x32x16_bf16.
//   R7 operand layout: the 16B prep record {xh|yh, zh|wh, xl|yl, zl|wl}
//   (w = -0.5*||p||^2, hi/lo bf16 split) is BOTH the B-fragment for all lanes
//   (one dwordx4 load, zero unpack) and the source of A:
//     lanes<32  (k0-7) : A={qh,1, qh,1}  ->  qh.rh + wh  +  qh.rl + wl
//     lanes>=32 (k8-15): A={ql,0, 0,0}   ->  ql.rh
//   (dropped ql.rl ~2^-17 relative)
//   min_j d2 = ||q||^2_fp32 - 2*max_n C, clamped at 0.
// Structure: NCHUNK=2 x 1024 blocks (4/CU), 4-wave blocks, no atomics in nn
// (disjoint kpart slots), LDS-transpose epilogue, manual unroll-2 prefetch.

#define BLOCK 256
#define WAVES 4
#define QPW 64        // queries per wave (two 32-row MFMA groups)
#define NCHUNK 2      // ref-dim split across blockIdx.y

typedef short short8 __attribute__((ext_vector_type(8)));
typedef float f32x16 __attribute__((ext_vector_type(16)));

union U16S { uint4 v; short8 s; };

__device__ __forceinline__ unsigned int bf16hi(float f) {
    __hip_bfloat16 h = __float2bfloat16(f);
    return (unsigned int)*reinterpret_cast<unsigned short*>(&h);
}
__device__ __forceinline__ float bf16f(unsigned int u) {
    unsigned short us = (unsigned short)u;
    __hip_bfloat16 h;
    *reinterpret_cast<unsigned short*>(&h) = us;
    return __bfloat162float(h);
}

__device__ __forceinline__ f32x16 mfma_bf16(short8 a, short8 b, f32x16 c) {
    f32x16 d;
    asm volatile("v_mfma_f32_32x32x16_bf16 %0, %1, %2, %3"
                 : "=v"(d) : "v"(a), "v"(b), "v"(c));
    return d;
}
// >=16 wait cycles between MFMA issue and VALU reads of dests (inline asm
// bypasses the compiler hazard recognizer); data-tied so folds can't hoist.
__device__ __forceinline__ void mfma_fence4(f32x16& a, f32x16& b, f32x16& c, f32x16& d) {
    asm volatile("s_nop 7\n\ts_nop 7" : "+v"(a), "+v"(b), "+v"(c), "+v"(d));
}

// Per point one 16B record {xh|yh, zh|wh, xl|yl, zl|wl} + fp32 ||p||^2 in q2.
// 4 points per thread (nG, nP are multiples of 4). Also zeroes out[0].
__global__ void prep_kernel(const float* __restrict__ gts, const float* __restrict__ preds,
                            int nG, int nP, uint4* __restrict__ recG, uint4* __restrict__ recP,
                            float* __restrict__ q2, float* out) {
    const int t = blockIdx.x * blockDim.x + threadIdx.x;
    if (t == 0) out[0] = 0.0f;
    const int i0 = t * 4;
    if (i0 >= nG + nP) return;
    const float* src;
    uint4* rec;
    if (i0 < nG) { src = gts + 3 * (size_t)i0;                rec = recG + i0; }
    else         { src = preds + 3 * (size_t)(i0 - nG);       rec = recP + (i0 - nG); }
    const float4 f0 = ((const float4*)src)[0];
    const float4 f1 = ((const float4*)src)[1];
    const float4 f2 = ((const float4*)src)[2];
    const float xs[4] = {f0.x, f0.w, f1.z, f2.y};
    const float ys[4] = {f0.y, f1.x, f1.w, f2.z};
    const float zs[4] = {f0.z, f1.y, f2.x, f2.w};
    float4 q2v;
    #pragma unroll
    for (int i = 0; i < 4; ++i) {
        const float x = xs[i], y = ys[i], z = zs[i];
        const float n2 = x * x + y * y + z * z;
        ((float*)&q2v)[i] = n2;
        const float w = -0.5f * n2;
        const unsigned int xh = bf16hi(x), yh = bf16hi(y), zh = bf16hi(z), wh = bf16hi(w);
        const unsigned int xl = bf16hi(x - bf16f(xh));
        const unsigned int yl = bf16hi(y - bf16f(yh));
        const unsigned int zl = bf16hi(z - bf16f(zh));
        const unsigned int wl = bf16hi(w - bf16f(wh));
        rec[i] = make_uint4(xh | (yh << 16), zh | (wh << 16),
                            xl | (yl << 16), zl | (wl << 16));
    }
    ((float4*)q2)[t] = q2v;      // q2 indexed globally over [0, nG+nP)
}

// kpart layout: float kpart[NCHUNK][nG + nP]; slot = blockIdx.y.
__global__ void __launch_bounds__(BLOCK, 4)
nn_kernel(const uint4* __restrict__ recG, const uint4* __restrict__ recP,
          float* __restrict__ kpart, int N, int M, int B) {
    const int z = blockIdx.z;
    const bool dirX = (z < B);
    const int b = dirX ? z : z - B;
    const int NQ = dirX ? N : M;
    const int NR = dirX ? M : N;
    const uint4* Qr = (dirX ? recG : recP) + (size_t)b * NQ;
    const uint4* Rr = (dirX ? recP : recG) + (size_t)b * NR;
    const int nGP = B * N + B * M;
    float* outK = kpart + (size_t)blockIdx.y * nGP + (dirX ? 0 : B * N) + (size_t)b * NQ;

    const int tid = threadIdx.x;
    const int lane = tid & 63;
    const int wave = tid >> 6;
    const int m = lane & 31;
    const bool hiK = lane >= 32;              // this half supplies k=8..15
    const int qBase = (blockIdx.x * WAVES + wave) * QPW;

    // ---- A fragments (two 32-row groups) from the same 16B records
    const uint4 q0 = Qr[qBase + m];
    const uint4 q1 = Qr[qBase + 32 + m];
    U16S a;
    a.v.x = hiK ? q0.z : q0.x;                                        // (qxh,qyh) | (qxl,qyl)
    a.v.y = hiK ? (q0.w & 0xFFFFu) : ((q0.y & 0xFFFFu) | 0x3F800000u); // (qzh,1) | (qzl,0)
    a.v.z = hiK ? 0u : a.v.x;                                          // (qxh,qyh) | 0
    a.v.w = hiK ? 0u : a.v.y;                                          // (qzh,1)   | 0
    const short8 A0 = a.s;
    a.v.x = hiK ? q1.z : q1.x;
    a.v.y = hiK ? (q1.w & 0xFFFFu) : ((q1.y & 0xFFFFu) | 0x3F800000u);
    a.v.z = hiK ? 0u : a.v.x;
    a.v.w = hiK ? 0u : a.v.y;
    const short8 A1 = a.s;

    f32x16 zc;
    #pragma unroll
    for (int r = 0; r < 16; ++r) zc[r] = 0.0f;
    f32x16 k0, k1;
    #pragma unroll
    for (int r = 0; r < 16; ++r) { k0[r] = -INFINITY; k1[r] = -INFINITY; }

    // B stream: each lane loads the FULL 16B record of ref point (tile+m);
    // both lane-halves read the same addresses (L1 broadcast). No unpack.
    const int chunk = NR / NCHUNK;
    const uint4* p = Rr + (size_t)blockIdx.y * chunk + m;
    const int iters = chunk / 64;             // 2 tiles (64 refs) per iter; even

    auto computeSet = [&](uint4 ta, uint4 tb) {
        U16S b0, b1;
        b0.v = ta; b1.v = tb;                 // pure reinterpret
        f32x16 c0 = mfma_bf16(A0, b0.s, zc);
        f32x16 c1 = mfma_bf16(A1, b0.s, zc);
        f32x16 c2 = mfma_bf16(A0, b1.s, zc);
        f32x16 c3 = mfma_bf16(A1, b1.s, zc);
        mfma_fence4(c0, c1, c2, c3);
        #pragma unroll
        for (int r = 0; r < 16; ++r) {
            k0[r] = fmaxf(fmaxf(c0[r], c2[r]), k0[r]);   // v_max3
            k1[r] = fmaxf(fmaxf(c1[r], c3[r]), k1[r]);
        }
    };

    // Manual unroll-2: prefetch registers rotate, no copy chain. Last-pair
    // overrun reads land in the adjacent ws region (recG->recP->q2) - safe.
    uint4 t0 = p[0], t1 = p[32];
    #pragma unroll 1
    for (int it = 0; it < iters; it += 2) {
        const uint4 u0 = p[64], u1 = p[96];
        computeSet(t0, t1);
        t0 = p[128]; t1 = p[160];
        computeSet(u0, u1);
        p += 128;
    }

    // ---- epilogue: LDS transpose, then each lane max-reduces one query row.
    // C/D layout: col=lane&31, row=(r&3)+8*(r>>2)+4*(lane>>5).
    __shared__ float sT[WAVES][64][36];       // +4 pad: aligned, conflict-free
    #pragma unroll
    for (int r = 0; r < 16; ++r) {
        const int row = (r & 3) + 8 * (r >> 2) + 4 * (lane >> 5);
        sT[wave][row][m]      = k0[r];        // group 0 -> rows 0..31
        sT[wave][32 + row][m] = k1[r];        // group 1 -> rows 32..63
    }
    // wave-private region; same-wave DS ops are ordered, compiler adds waits.
    const float4* rowp = (const float4*)&sT[wave][lane][0];
    float4 m01 = rowp[0];
    #pragma unroll
    for (int kk = 1; kk < 8; ++kk) {
        const float4 tt = rowp[kk];
        m01.x = fmaxf(m01.x, tt.x); m01.y = fmaxf(m01.y, tt.y);
        m01.z = fmaxf(m01.z, tt.z); m01.w = fmaxf(m01.w, tt.w);
    }
    const float cmax = fmaxf(fmaxf(m01.x, m01.y), fmaxf(m01.z, m01.w));
    outK[qBase + lane] = cmax;                // coalesced, no atomics
}

// d2 = max(0, q2 - 2*max(kpart[0], kpart[1])); weighted means, one
// atomicAdd per block.
__global__ void __launch_bounds__(BLOCK)
reduce_kernel(const float* __restrict__ kpart, const float* __restrict__ q2,
              int nG, int nP, float invx, float invy, float* __restrict__ out) {
    const int total = nG + nP;
    float local = 0.0f;
    for (int idx = blockIdx.x * blockDim.x + threadIdx.x; idx < total;
         idx += gridDim.x * blockDim.x) {
        const float c = fmaxf(kpart[idx], kpart[total + idx]);
        const float inv = (idx < nG) ? invx : invy;
        local += fmaxf(q2[idx] - 2.0f * c, 0.0f) * inv;
    }
    __shared__ float waveSums[BLOCK / 64];
    float v = local;
    #pragma unroll
    for (int off = 32; off; off >>= 1) v += __shfl_xor(v, off);
    if ((threadIdx.x & 63) == 0) waveSums[threadIdx.x >> 6] = v;
    __syncthreads();
    if (threadIdx.x == 0) {
        float s = 0.0f;
        #pragma unroll
        for (int w = 0; w < BLOCK / 64; ++w) s += waveSums[w];
        atomicAdd(out, s);
    }
}

extern "C" void kernel_launch(void* const* d_in, const int* in_sizes, int n_in,
                              void* d_out, int out_size, void* d_ws, size_t ws_size,
                              hipStream_t stream) {
    const float* gts   = (const float*)d_in[0];   // [B, N, 3]
    const float* preds = (const float*)d_in[1];   // [B, M, 3]
    float* out = (float*)d_out;

    const int B = 8;
    const int N = in_sizes[0] / (B * 3);
    const int M = in_sizes[1] / (B * 3);
    const int nG = B * N, nP = B * M;

    uint4* recG  = (uint4*)d_ws;                  // nG uint4 (1 MB)
    uint4* recP  = recG + nG;                     // nP uint4 (1 MB)
    float* q2    = (float*)(recP + nP);           // nG+nP floats (0.5 MB)
    float* kpart = q2 + (nG + nP);                // NCHUNK*(nG+nP) floats (1 MB)

    prep_kernel<<<((nG + nP) / 4 + BLOCK - 1) / BLOCK, BLOCK, 0, stream>>>(
        gts, preds, nG, nP, recG, recP, q2, out);

    dim3 grid(N / (WAVES * QPW), NCHUNK, 2 * B);  // 32 x 2 x 16 = 1024 = 4/CU
    nn_kernel<<<grid, BLOCK, 0, stream>>>(recG, recP, kpart, N, M, B);

    reduce_kernel<<<256, BLOCK, 0, stream>>>(
        kpart, q2, nG, nP, 1.0f / (float)nG, 1.0f / (float)nP, out);
}

// Round 8
// 103.282 us; speedup vs baseline: 2.3043x; 2.3043x over previous
//
#include <hip/hip_runtime.h>
#include <hip/hip_bf16.h>
#include <math.h>

// Chamfer distance via K-packed MFMA, B=8, N=M=8192, D=3, fp32.
//   C[m][n] = q_m.r_n - 0.5*||r_n||^2 via ONE v_mfma_f32_32x32x16_bf16.
//   Operand layout (R7): the 16B prep record {xh|yh, zh|wh, xl|yl, zl|wl}
//   (w = -0.5*||p||^2, hi/lo bf16 split) is BOTH the B-fragment for all lanes
//   (one dwordx4 load, zero unpack) and the source of A:
//     lanes<32  (k0-7) : A={qh,1, qh,1}  ->  qh.rh + wh  +  qh.rl + wl
//     lanes>=32 (k8-15): A={ql,0, 0,0}   ->  ql.rh
//   (dropped ql.rl ~2^-17 relative)
//   min_j d2 = ||q||^2_fp32 - 2*max_n C, clamped at 0.
// R8: register budget fixed — launch_bounds(256,3) (170 VGPR cap) and
// distance-1 prefetch only (4 live uint4). R7's (256,4)=128 cap + 6-slot
// prefetch spilled accumulators to scratch (WRITE_SIZE 706 MB, 2.4x slower).

#define BLOCK 256
#define WAVES 4
#define QPW 64        // queries per wave (two 32-row MFMA groups)
#define NCHUNK 2      // ref-dim split across blockIdx.y

typedef short short8 __attribute__((ext_vector_type(8)));
typedef float f32x16 __attribute__((ext_vector_type(16)));

union U16S { uint4 v; short8 s; };

__device__ __forceinline__ unsigned int bf16hi(float f) {
    __hip_bfloat16 h = __float2bfloat16(f);
    return (unsigned int)*reinterpret_cast<unsigned short*>(&h);
}
__device__ __forceinline__ float bf16f(unsigned int u) {
    unsigned short us = (unsigned short)u;
    __hip_bfloat16 h;
    *reinterpret_cast<unsigned short*>(&h) = us;
    return __bfloat162float(h);
}

__device__ __forceinline__ f32x16 mfma_bf16(short8 a, short8 b, f32x16 c) {
    f32x16 d;
    asm volatile("v_mfma_f32_32x32x16_bf16 %0, %1, %2, %3"
                 : "=v"(d) : "v"(a), "v"(b), "v"(c));
    return d;
}
// >=16 wait cycles between MFMA issue and VALU reads of dests (inline asm
// bypasses the compiler hazard recognizer); data-tied so folds can't hoist.
__device__ __forceinline__ void mfma_fence4(f32x16& a, f32x16& b, f32x16& c, f32x16& d) {
    asm volatile("s_nop 7\n\ts_nop 7" : "+v"(a), "+v"(b), "+v"(c), "+v"(d));
}

// Per point one 16B record {xh|yh, zh|wh, xl|yl, zl|wl} + fp32 ||p||^2 in q2.
// 4 points per thread (nG, nP are multiples of 4). Also zeroes out[0].
__global__ void prep_kernel(const float* __restrict__ gts, const float* __restrict__ preds,
                            int nG, int nP, uint4* __restrict__ recG, uint4* __restrict__ recP,
                            float* __restrict__ q2, float* out) {
    const int t = blockIdx.x * blockDim.x + threadIdx.x;
    if (t == 0) out[0] = 0.0f;
    const int i0 = t * 4;
    if (i0 >= nG + nP) return;
    const float* src;
    uint4* rec;
    if (i0 < nG) { src = gts + 3 * (size_t)i0;                rec = recG + i0; }
    else         { src = preds + 3 * (size_t)(i0 - nG);       rec = recP + (i0 - nG); }
    const float4 f0 = ((const float4*)src)[0];
    const float4 f1 = ((const float4*)src)[1];
    const float4 f2 = ((const float4*)src)[2];
    const float xs[4] = {f0.x, f0.w, f1.z, f2.y};
    const float ys[4] = {f0.y, f1.x, f1.w, f2.z};
    const float zs[4] = {f0.z, f1.y, f2.x, f2.w};
    float4 q2v;
    #pragma unroll
    for (int i = 0; i < 4; ++i) {
        const float x = xs[i], y = ys[i], z = zs[i];
        const float n2 = x * x + y * y + z * z;
        ((float*)&q2v)[i] = n2;
        const float w = -0.5f * n2;
        const unsigned int xh = bf16hi(x), yh = bf16hi(y), zh = bf16hi(z), wh = bf16hi(w);
        const unsigned int xl = bf16hi(x - bf16f(xh));
        const unsigned int yl = bf16hi(y - bf16f(yh));
        const unsigned int zl = bf16hi(z - bf16f(zh));
        const unsigned int wl = bf16hi(w - bf16f(wh));
        rec[i] = make_uint4(xh | (yh << 16), zh | (wh << 16),
                            xl | (yl << 16), zl | (wl << 16));
    }
    ((float4*)q2)[t] = q2v;      // q2 indexed globally over [0, nG+nP)
}

// kpart layout: float kpart[NCHUNK][nG + nP]; slot = blockIdx.y.
__global__ void __launch_bounds__(BLOCK, 3)
nn_kernel(const uint4* __restrict__ recG, const uint4* __restrict__ recP,
          float* __restrict__ kpart, int N, int M, int B) {
    const int z = blockIdx.z;
    const bool dirX = (z < B);
    const int b = dirX ? z : z - B;
    const int NQ = dirX ? N : M;
    const int NR = dirX ? M : N;
    const uint4* Qr = (dirX ? recG : recP) + (size_t)b * NQ;
    const uint4* Rr = (dirX ? recP : recG) + (size_t)b * NR;
    const int nGP = B * N + B * M;
    float* outK = kpart + (size_t)blockIdx.y * nGP + (dirX ? 0 : B * N) + (size_t)b * NQ;

    const int tid = threadIdx.x;
    const int lane = tid & 63;
    const int wave = tid >> 6;
    const int m = lane & 31;
    const bool hiK = lane >= 32;              // this half supplies k=8..15
    const int qBase = (blockIdx.x * WAVES + wave) * QPW;

    // ---- A fragments (two 32-row groups) from the same 16B records
    const uint4 q0 = Qr[qBase + m];
    const uint4 q1 = Qr[qBase + 32 + m];
    U16S a;
    a.v.x = hiK ? q0.z : q0.x;                                         // (qxh,qyh)|(qxl,qyl)
    a.v.y = hiK ? (q0.w & 0xFFFFu) : ((q0.y & 0xFFFFu) | 0x3F800000u); // (qzh,1)|(qzl,0)
    a.v.z = hiK ? 0u : a.v.x;                                          // (qxh,qyh)|0
    a.v.w = hiK ? 0u : a.v.y;                                          // (qzh,1)  |0
    const short8 A0 = a.s;
    a.v.x = hiK ? q1.z : q1.x;
    a.v.y = hiK ? (q1.w & 0xFFFFu) : ((q1.y & 0xFFFFu) | 0x3F800000u);
    a.v.z = hiK ? 0u : a.v.x;
    a.v.w = hiK ? 0u : a.v.y;
    const short8 A1 = a.s;

    f32x16 zc;
    #pragma unroll
    for (int r = 0; r < 16; ++r) zc[r] = 0.0f;
    f32x16 k0, k1;
    #pragma unroll
    for (int r = 0; r < 16; ++r) { k0[r] = -INFINITY; k1[r] = -INFINITY; }

    // B stream: each lane loads the FULL 16B record of ref point (tile+m);
    // both lane-halves read the same addresses (L1 broadcast). No unpack.
    const int chunk = NR / NCHUNK;
    const uint4* p = Rr + (size_t)blockIdx.y * chunk + m;
    const int iters = chunk / 64;             // 2 tiles (64 refs) per iter

    // distance-1 prefetch: exactly 4 uint4 in registers at any time.
    uint4 t0 = p[0], t1 = p[32];
    #pragma unroll 1
    for (int it = 0; it < iters; ++it) {
        // last-iter overrun lands in the adjacent ws region — loaded, unused.
        const uint4 n0 = p[64];
        const uint4 n1 = p[96];

        U16S b0, b1;
        b0.v = t0; b1.v = t1;                 // pure reinterpret, zero VALU
        f32x16 c0 = mfma_bf16(A0, b0.s, zc);
        f32x16 c1 = mfma_bf16(A1, b0.s, zc);
        f32x16 c2 = mfma_bf16(A0, b1.s, zc);
        f32x16 c3 = mfma_bf16(A1, b1.s, zc);
        mfma_fence4(c0, c1, c2, c3);
        #pragma unroll
        for (int r = 0; r < 16; ++r) {
            k0[r] = fmaxf(fmaxf(c0[r], c2[r]), k0[r]);   // v_max3
            k1[r] = fmaxf(fmaxf(c1[r], c3[r]), k1[r]);
        }

        t0 = n0; t1 = n1;
        p += 64;
    }

    // ---- epilogue: LDS transpose, then each lane max-reduces one query row.
    // C/D layout: col=lane&31, row=(r&3)+8*(r>>2)+4*(lane>>5).
    __shared__ float sT[WAVES][64][36];       // +4 pad: aligned, conflict-free
    #pragma unroll
    for (int r = 0; r < 16; ++r) {
        const int row = (r & 3) + 8 * (r >> 2) + 4 * (lane >> 5);
        sT[wave][row][m]      = k0[r];        // group 0 -> rows 0..31
        sT[wave][32 + row][m] = k1[r];        // group 1 -> rows 32..63
    }
    // wave-private region; same-wave DS ops are ordered, compiler adds waits.
    const float4* rowp = (const float4*)&sT[wave][lane][0];
    float4 m01 = rowp[0];
    #pragma unroll
    for (int kk = 1; kk < 8; ++kk) {
        const float4 tt = rowp[kk];
        m01.x = fmaxf(m01.x, tt.x); m01.y = fmaxf(m01.y, tt.y);
        m01.z = fmaxf(m01.z, tt.z); m01.w = fmaxf(m01.w, tt.w);
    }
    const float cmax = fmaxf(fmaxf(m01.x, m01.y), fmaxf(m01.z, m01.w));
    outK[qBase + lane] = cmax;                // coalesced, no atomics
}

// d2 = max(0, q2 - 2*max(kpart[0], kpart[1])); weighted means, one
// atomicAdd per block.
__global__ void __launch_bounds__(BLOCK)
reduce_kernel(const float* __restrict__ kpart, const float* __restrict__ q2,
              int nG, int nP, float invx, float invy, float* __restrict__ out) {
    const int total = nG + nP;
    float local = 0.0f;
    for (int idx = blockIdx.x * blockDim.x + threadIdx.x; idx < total;
         idx += gridDim.x * blockDim.x) {
        const float c = fmaxf(kpart[idx], kpart[total + idx]);
        const float inv = (idx < nG) ? invx : invy;
        local += fmaxf(q2[idx] - 2.0f * c, 0.0f) * inv;
    }
    __shared__ float waveSums[BLOCK / 64];
    float v = local;
    #pragma unroll
    for (int off = 32; off; off >>= 1) v += __shfl_xor(v, off);
    if ((threadIdx.x & 63) == 0) waveSums[threadIdx.x >> 6] = v;
    __syncthreads();
    if (threadIdx.x == 0) {
        float s = 0.0f;
        #pragma unroll
        for (int w = 0; w < BLOCK / 64; ++w) s += waveSums[w];
        atomicAdd(out, s);
    }
}

extern "C" void kernel_launch(void* const* d_in, const int* in_sizes, int n_in,
                              void* d_out, int out_size, void* d_ws, size_t ws_size,
                              hipStream_t stream) {
    const float* gts   = (const float*)d_in[0];   // [B, N, 3]
    const float* preds = (const float*)d_in[1];   // [B, M, 3]
    float* out = (float*)d_out;

    const int B = 8;
    const int N = in_sizes[0] / (B * 3);
    const int M = in_sizes[1] / (B * 3);
    const int nG = B * N, nP = B * M;

    uint4* recG  = (uint4*)d_ws;                  // nG uint4 (1 MB)
    uint4* recP  = recG + nG;                     // nP uint4 (1 MB)
    float* q2    = (float*)(recP + nP);           // nG+nP floats (0.5 MB)
    float* kpart = q2 + (nG + nP);                // NCHUNK*(nG+nP) floats (1 MB)

    prep_kernel<<<((nG + nP) / 4 + BLOCK - 1) / BLOCK, BLOCK, 0, stream>>>(
        gts, preds, nG, nP, recG, recP, q2, out);

    dim3 grid(N / (WAVES * QPW), NCHUNK, 2 * B);  // 32 x 2 x 16 = 1024 blocks
    nn_kernel<<<grid, BLOCK, 0, stream>>>(recG, recP, kpart, N, M, B);

    reduce_kernel<<<256, BLOCK, 0, stream>>>(
        kpart, q2, nG, nP, 1.0f / (float)nG, 1.0f / (float)nP, out);
}